// Round 1
// baseline (1909.179 us; speedup 1.0000x reference)
//
#include <hip/hip_runtime.h>

#define N_TOTAL   262144
#define ROWS      128        // rows per conv block
#define GT_STRIDE 129        // padded LDS stride (dwords): reads conflict-free, writes 2-way(free)
#define BN_EPS    1e-3f

// ---------------------------------------------------------------------------
// Conv: out[n,c] = bias[c] + sum_k sum_ci feat[idx[n,k],ci] * W[k,ci,c]
// Block: 256 threads = 4 waves. Tile: 128 rows x 64 cols.
//   wave w: rows 64*(w>>1) .. +63  (lane = row), cols 32*(w&1) .. +31 (acc[32])
// Weights are wave-uniform -> SGPR broadcast (readfirstlane-forced).
// Epilogue: store out, butterfly-reduce per-channel sum/sumsq, atomicAdd to ws.
// ---------------------------------------------------------------------------
__global__ void sparse_conv3x3_kernel(const float* __restrict__ feat,
                                      const float* __restrict__ W,
                                      const float* __restrict__ bias,
                                      const int*   __restrict__ nb,
                                      float* __restrict__ out,
                                      float* __restrict__ gstats)
{
    __shared__ float GT[64 * GT_STRIDE];   // transposed gathered tile: GT[ci][r], ~33 KB
    __shared__ int   IL[ROWS * 9];         // neighbor idx tile

    const int tid  = threadIdx.x;
    const int n0   = blockIdx.x * ROWS;

    // stage neighbor indices for the whole tile (coalesced)
    for (int i = tid; i < ROWS * 9; i += 256) IL[i] = nb[n0 * 9 + i];

    const int lane  = tid & 63;
    const int wave  = tid >> 6;
    const int rbase = (wave >> 1) << 6;                              // 0 or 64
    const int c0    = __builtin_amdgcn_readfirstlane((wave & 1) << 5); // 0 or 32, forced SGPR

    // staging mapping: 16 lanes per row, float4 each
    const int l16 = tid & 15;
    const int rr  = tid >> 4;    // 0..15

    float acc[32];
#pragma unroll
    for (int j = 0; j < 32; ++j) acc[j] = 0.f;

    for (int k = 0; k < 9; ++k) {
        __syncthreads();   // protect GT from previous iteration's readers
        // ---- gather-stage 128 feature rows into transposed LDS ----
#pragma unroll
        for (int it = 0; it < 8; ++it) {
            const int r   = rr + it * 16;
            const int idx = IL[r * 9 + k];
            float4 v = make_float4(0.f, 0.f, 0.f, 0.f);
            if (idx >= 0)
                v = *(const float4*)(feat + ((size_t)idx << 6) + (l16 << 2));
            const int ci0 = l16 << 2;
            GT[(ci0    ) * GT_STRIDE + r] = v.x;
            GT[(ci0 + 1) * GT_STRIDE + r] = v.y;
            GT[(ci0 + 2) * GT_STRIDE + r] = v.z;
            GT[(ci0 + 3) * GT_STRIDE + r] = v.w;
        }
        __syncthreads();
        // ---- compute: per ci, 1 LDS read (per-lane G) + 32 FMA w/ SGPR weight ----
        const float* wk = W + k * 4096 + c0;   // wave-uniform pointer
#pragma unroll 2
        for (int ci = 0; ci < 64; ++ci) {
            const float g = GT[ci * GT_STRIDE + rbase + lane];
            const float* wr = wk + ci * 64;    // uniform -> s_load_dwordx16 expected
#pragma unroll
            for (int j = 0; j < 32; ++j)
                acc[j] = fmaf(g, wr[j], acc[j]);
        }
    }

    // ---- epilogue: bias, store out ----
    const int r = rbase + lane;
#pragma unroll
    for (int j = 0; j < 32; ++j) acc[j] += bias[c0 + j];

    float4* orow = (float4*)(out + (size_t)(n0 + r) * 64 + c0);
#pragma unroll
    for (int jq = 0; jq < 8; ++jq)
        orow[jq] = make_float4(acc[4*jq], acc[4*jq+1], acc[4*jq+2], acc[4*jq+3]);

    // ---- BN partial sums: butterfly over 64 lanes (rows), per channel ----
#pragma unroll
    for (int j = 0; j < 32; ++j) {
        float s  = acc[j];
        float sq = acc[j] * acc[j];
#pragma unroll
        for (int d = 1; d < 64; d <<= 1) {
            s  += __shfl_xor(s,  d, 64);
            sq += __shfl_xor(sq, d, 64);
        }
        if (lane == 0) {
            atomicAdd(&gstats[c0 + j],      s);
            atomicAdd(&gstats[64 + c0 + j], sq);
        }
    }
}

// ---------------------------------------------------------------------------
// Stats: scale[c] = gamma[c]*rsqrt(var+eps); shift[c] = beta[c]-mean[c]*scale[c]
// ---------------------------------------------------------------------------
__global__ void bn_stats_kernel(const float* __restrict__ gamma,
                                const float* __restrict__ beta,
                                float* __restrict__ gstats)
{
    const int c = threadIdx.x;   // 64 threads
    const float inv_n = 1.f / (float)N_TOTAL;
    const float mean  = gstats[c] * inv_n;
    const float var   = gstats[64 + c] * inv_n - mean * mean;
    const float sc    = gamma[c] * rsqrtf(var + BN_EPS);
    gstats[128 + c] = sc;
    gstats[192 + c] = beta[c] - mean * sc;
}

// ---------------------------------------------------------------------------
// Apply: out_bn = out * scale[c] + shift[c]   (float4, memory-bound)
// ---------------------------------------------------------------------------
__global__ void bn_apply_kernel(const float* __restrict__ out,
                                const float* __restrict__ gstats,
                                float* __restrict__ out_bn)
{
    const size_t i  = (size_t)blockIdx.x * blockDim.x + threadIdx.x;  // float4 idx
    const int    c4 = ((int)i & 15) << 2;
    const float4 v  = ((const float4*)out)[i];
    const float4 sc = *(const float4*)(gstats + 128 + c4);
    const float4 sh = *(const float4*)(gstats + 192 + c4);
    float4 o;
    o.x = fmaf(v.x, sc.x, sh.x);
    o.y = fmaf(v.y, sc.y, sh.y);
    o.z = fmaf(v.z, sc.z, sh.z);
    o.w = fmaf(v.w, sc.w, sh.w);
    ((float4*)out_bn)[i] = o;
}

extern "C" void kernel_launch(void* const* d_in, const int* in_sizes, int n_in,
                              void* d_out, int out_size, void* d_ws, size_t ws_size,
                              hipStream_t stream)
{
    const float* feat  = (const float*)d_in[0];   // (N, 64)
    const float* W     = (const float*)d_in[1];   // (9, 64, 64)
    const float* bias  = (const float*)d_in[2];   // (64,)
    const float* gamma = (const float*)d_in[3];   // (64,)
    const float* beta  = (const float*)d_in[4];   // (64,)
    const int*   nb    = (const int*)  d_in[5];   // (N, 9)

    float* out    = (float*)d_out;                       // first N*64 floats
    float* out_bn = out + (size_t)N_TOTAL * 64;          // second N*64 floats
    float* gstats = (float*)d_ws;                        // [0:64) sum, [64:128) sumsq,
                                                         // [128:192) scale, [192:256) shift

    hipMemsetAsync(d_ws, 0, 256 * sizeof(float), stream);

    sparse_conv3x3_kernel<<<N_TOTAL / ROWS, 256, 0, stream>>>(feat, W, bias, nb, out, gstats);
    bn_stats_kernel<<<1, 64, 0, stream>>>(gamma, beta, gstats);
    bn_apply_kernel<<<(N_TOTAL * 64 / 4) / 256, 256, 0, stream>>>(out, gstats, out_bn);
}

// Round 2
// 343.467 us; speedup vs baseline: 5.5586x; 5.5586x over previous
//
#include <hip/hip_runtime.h>
#include <hip/hip_bf16.h>

#define N_TOTAL 262144
#define BN_EPS  1e-3f

typedef float f32x4  __attribute__((ext_vector_type(4)));
typedef short bf16x8 __attribute__((ext_vector_type(8)));

// ws layout (bytes):
//   [0, 1024)        : gstats — 256 floats: sum[64], sumsq[64], scale[64], shift[64]
//   [1024, 74752)    : wfrag  — 72 B-fragments x 64 lanes x 8 bf16 (36864 ushort)
//   [131072, +33.5MB): featb  — bf16 copy of feat (N x 64), only if ws_size allows
#define WFRAG_OFF 1024
#define FEATB_OFF 131072

// ---------------------------------------------------------------------------
// Prepass 1: W (9,64,64) fp32 -> fragment-ordered bf16.
// frag f = (k9*2 + kk)*4 + nb ; lane L ; elem j:
//   k_local = (L>>4)*8 + j  (K within the 32-chunk), n = nb*16 + (L&15)
//   src = W[k9][kk*32 + k_local][n]
// ---------------------------------------------------------------------------
__global__ void weight_pack_kernel(const float* __restrict__ W,
                                   unsigned short* __restrict__ wfrag)
{
    const int e = blockIdx.x * 256 + threadIdx.x;   // 144 blocks * 256 = 36864
    const int f  = e >> 9;
    const int r  = e & 511;
    const int L  = r >> 3;
    const int j  = r & 7;
    const int nb = f & 3;
    const int kk = (f >> 2) & 1;
    const int k9 = f >> 3;
    const int kci = kk * 32 + ((L >> 4) << 3) + j;
    const int n   = nb * 16 + (L & 15);
    __hip_bfloat16 b = __float2bfloat16(W[k9 * 4096 + kci * 64 + n]);
    wfrag[e] = *reinterpret_cast<unsigned short*>(&b);
}

// ---------------------------------------------------------------------------
// Prepass 2: feat fp32 -> row-major bf16 (memory-bound, ~15us)
// ---------------------------------------------------------------------------
__global__ void feat_pack_kernel(const float* __restrict__ feat,
                                 unsigned short* __restrict__ featb)
{
    const size_t i = (size_t)blockIdx.x * 256 + threadIdx.x;  // float4 units
    const float4 v = ((const float4*)feat)[i];
    union { __hip_bfloat162 h[2]; uint2 u; } p;
    p.h[0] = __float22bfloat162_rn(make_float2(v.x, v.y));
    p.h[1] = __float22bfloat162_rn(make_float2(v.z, v.w));
    ((uint2*)featb)[i] = p.u;
}

__device__ __forceinline__ bf16x8 cvt8(float4 a, float4 b)
{
    union { bf16x8 v; __hip_bfloat162 h[4]; } u;
    u.h[0] = __float22bfloat162_rn(make_float2(a.x, a.y));
    u.h[1] = __float22bfloat162_rn(make_float2(a.z, a.w));
    u.h[2] = __float22bfloat162_rn(make_float2(b.x, b.y));
    u.h[3] = __float22bfloat162_rn(make_float2(b.z, b.w));
    return u.v;
}

// ---------------------------------------------------------------------------
// Conv via MFMA. Block = 256 thr = 4 waves; block tile 256 rows x 64 cols.
// Wave tile 64 rows x 64 cols = 4x4 frags of 16x16 (f32x4 acc each = 64 AGPR).
// K = 9 taps x 64 ci, consumed as 18 chunks of 32 (16x16x32 bf16 MFMA).
// A-frag: lane m=(lane&15)=row, k=quad*8+j -> 16 contiguous bf16 bytes/lane.
// B-frag: pre-packed fragment order -> dwordx4 at wfrag + frag*1KB + lane*16.
// No LDS / no barriers in the K-loop -> waves hide gather latency freely.
// ---------------------------------------------------------------------------
template<bool BF16PRE>
__global__ __launch_bounds__(256, 2)
void conv_mfma_kernel(const float* __restrict__ feat,
                      const unsigned short* __restrict__ featb,
                      const unsigned short* __restrict__ wfrag,
                      const float* __restrict__ bias,
                      const int*   __restrict__ nb9,
                      float* __restrict__ out,
                      float* __restrict__ gstats)
{
    __shared__ int IL[256 * 9];

    const int tid  = threadIdx.x;
    const int lane = tid & 63;
    const int wave = tid >> 6;
    const int quad = lane >> 4;
    const int l16  = lane & 15;

    // stage neighbor indices for the block's 256 rows (coalesced)
    for (int i = tid; i < 256 * 9; i += 256)
        IL[i] = nb9[(size_t)blockIdx.x * 2304 + i];
    __syncthreads();   // only barrier in the kernel

    f32x4 acc[4][4];
#pragma unroll
    for (int mb = 0; mb < 4; ++mb)
#pragma unroll
        for (int nbv = 0; nbv < 4; ++nbv)
            acc[mb][nbv] = (f32x4){0.f, 0.f, 0.f, 0.f};

    const int rowbase = wave * 64;

    for (int k9 = 0; k9 < 9; ++k9) {
        // per-row gather indices for this tap (idx shared by both kk chunks)
        int idx[4];
#pragma unroll
        for (int mb = 0; mb < 4; ++mb)
            idx[mb] = IL[(rowbase + mb * 16 + l16) * 9 + k9];

        bf16x8 A[2][4], Bf[2][4];
#pragma unroll
        for (int kk = 0; kk < 2; ++kk) {
#pragma unroll
            for (int mb = 0; mb < 4; ++mb) {
                const int id  = idx[mb];
                const size_t row = (size_t)(id < 0 ? 0 : id);
                bf16x8 a;
                if (BF16PRE) {
                    a = *(const bf16x8*)(featb + (row << 6) + kk * 32 + quad * 8);
                } else {
                    const float* p = feat + (row << 6) + kk * 32 + quad * 8;
                    a = cvt8(*(const float4*)p, *(const float4*)(p + 4));
                }
                A[kk][mb] = (id < 0) ? (bf16x8)0 : a;
            }
#pragma unroll
            for (int nbv = 0; nbv < 4; ++nbv)
                Bf[kk][nbv] = *(const bf16x8*)(wfrag
                              + (((k9 * 2 + kk) * 4 + nbv) << 9) + lane * 8);
        }
#pragma unroll
        for (int kk = 0; kk < 2; ++kk)
#pragma unroll
            for (int mb = 0; mb < 4; ++mb)
#pragma unroll
                for (int nbv = 0; nbv < 4; ++nbv)
                    acc[mb][nbv] = __builtin_amdgcn_mfma_f32_16x16x32_bf16(
                        A[kk][mb], Bf[kk][nbv], acc[mb][nbv], 0, 0, 0);
    }

    // ---- epilogue: bias, store out, BN partial sums ----
    const size_t row0 = (size_t)blockIdx.x * 256 + rowbase;
    float s[4], sq[4];
#pragma unroll
    for (int nbv = 0; nbv < 4; ++nbv) { s[nbv] = 0.f; sq[nbv] = 0.f; }

#pragma unroll
    for (int nbv = 0; nbv < 4; ++nbv) {
        const float b = bias[nbv * 16 + l16];
#pragma unroll
        for (int mb = 0; mb < 4; ++mb) {
            const f32x4 v = acc[mb][nbv];
#pragma unroll
            for (int i = 0; i < 4; ++i) {
                const float o = v[i] + b;
                out[(row0 + mb * 16 + quad * 4 + i) * 64 + nbv * 16 + l16] = o;
                s[nbv]  += o;
                sq[nbv] += o * o;
            }
        }
    }
#pragma unroll
    for (int nbv = 0; nbv < 4; ++nbv) {
        float ss = s[nbv], qq = sq[nbv];
        ss += __shfl_xor(ss, 16, 64);  qq += __shfl_xor(qq, 16, 64);
        ss += __shfl_xor(ss, 32, 64);  qq += __shfl_xor(qq, 32, 64);
        if (quad == 0) {
            atomicAdd(&gstats[nbv * 16 + l16],      ss);
            atomicAdd(&gstats[64 + nbv * 16 + l16], qq);
        }
    }
}

// ---------------------------------------------------------------------------
__global__ void bn_stats_kernel(const float* __restrict__ gamma,
                                const float* __restrict__ beta,
                                float* __restrict__ gstats)
{
    const int c = threadIdx.x;   // 64 threads
    const float inv_n = 1.f / (float)N_TOTAL;
    const float mean  = gstats[c] * inv_n;
    const float var   = gstats[64 + c] * inv_n - mean * mean;
    const float sc    = gamma[c] * rsqrtf(var + BN_EPS);
    gstats[128 + c] = sc;
    gstats[192 + c] = beta[c] - mean * sc;
}

__global__ void bn_apply_kernel(const float* __restrict__ out,
                                const float* __restrict__ gstats,
                                float* __restrict__ out_bn)
{
    const size_t i  = (size_t)blockIdx.x * blockDim.x + threadIdx.x;  // float4 idx
    const int    c4 = ((int)i & 15) << 2;
    const float4 v  = ((const float4*)out)[i];
    const float4 sc = *(const float4*)(gstats + 128 + c4);
    const float4 sh = *(const float4*)(gstats + 192 + c4);
    float4 o;
    o.x = fmaf(v.x, sc.x, sh.x);
    o.y = fmaf(v.y, sc.y, sh.y);
    o.z = fmaf(v.z, sc.z, sh.z);
    o.w = fmaf(v.w, sc.w, sh.w);
    ((float4*)out_bn)[i] = o;
}

extern "C" void kernel_launch(void* const* d_in, const int* in_sizes, int n_in,
                              void* d_out, int out_size, void* d_ws, size_t ws_size,
                              hipStream_t stream)
{
    const float* feat  = (const float*)d_in[0];   // (N, 64)
    const float* W     = (const float*)d_in[1];   // (9, 64, 64)
    const float* bias  = (const float*)d_in[2];
    const float* gamma = (const float*)d_in[3];
    const float* beta  = (const float*)d_in[4];
    const int*   nb9   = (const int*)  d_in[5];   // (N, 9)

    float* out    = (float*)d_out;
    float* out_bn = out + (size_t)N_TOTAL * 64;

    float*          gstats = (float*)d_ws;
    unsigned short* wfrag  = (unsigned short*)((char*)d_ws + WFRAG_OFF);
    unsigned short* featb  = (unsigned short*)((char*)d_ws + FEATB_OFF);

    const bool use_featb =
        ws_size >= (size_t)FEATB_OFF + (size_t)N_TOTAL * 64 * sizeof(unsigned short);

    hipMemsetAsync(d_ws, 0, 256 * sizeof(float), stream);
    weight_pack_kernel<<<144, 256, 0, stream>>>(W, wfrag);
    if (use_featb) {
        feat_pack_kernel<<<(N_TOTAL * 64 / 4) / 256, 256, 0, stream>>>(feat, featb);
        conv_mfma_kernel<true><<<N_TOTAL / 256, 256, 0, stream>>>(
            feat, featb, wfrag, bias, nb9, out, gstats);
    } else {
        conv_mfma_kernel<false><<<N_TOTAL / 256, 256, 0, stream>>>(
            feat, featb, wfrag, bias, nb9, out, gstats);
    }
    bn_stats_kernel<<<1, 64, 0, stream>>>(gamma, beta, gstats);
    bn_apply_kernel<<<(N_TOTAL * 64 / 4) / 256, 256, 0, stream>>>(out, gstats, out_bn);
}

// Round 3
// 323.622 us; speedup vs baseline: 5.8994x; 1.0613x over previous
//
#include <hip/hip_runtime.h>
#include <hip/hip_bf16.h>

#define N_TOTAL 262144
#define BN_EPS  1e-3f

typedef float f32x4  __attribute__((ext_vector_type(4)));
typedef short bf16x8 __attribute__((ext_vector_type(8)));

// ws layout (bytes):
//   [0, 1024)        : gstats — 256 floats: sum[64], sumsq[64] (+spare)
//   [1024, 74752)    : wfrag  — 72 B-fragments x 64 lanes x 8 bf16
//   [131072, +33.5MB): featb  — bf16 copy of feat (N x 64)
#define WFRAG_OFF 1024
#define FEATB_OFF 131072
#define FEAT_BLOCKS 16384     // N*64/4/256 float4-convert blocks
#define WPACK_BLOCKS 144

// ---------------------------------------------------------------------------
// Fused prepare: feat fp32->bf16, W -> fragment-ordered bf16, gstats zero.
// ---------------------------------------------------------------------------
template<bool DO_FEAT>
__global__ void prepare_kernel(const float* __restrict__ feat,
                               unsigned short* __restrict__ featb,
                               const float* __restrict__ W,
                               unsigned short* __restrict__ wfrag,
                               float* __restrict__ gstats)
{
    const int b = blockIdx.x;
    if (b < FEAT_BLOCKS) {
        if (DO_FEAT) {
            const size_t i = (size_t)b * 256 + threadIdx.x;   // float4 units
            const float4 v = ((const float4*)feat)[i];
            union { __hip_bfloat162 h[2]; uint2 u; } p;
            p.h[0] = __float22bfloat162_rn(make_float2(v.x, v.y));
            p.h[1] = __float22bfloat162_rn(make_float2(v.z, v.w));
            ((uint2*)featb)[i] = p.u;
        }
    } else if (b < FEAT_BLOCKS + WPACK_BLOCKS) {
        const int e = (b - FEAT_BLOCKS) * 256 + threadIdx.x;  // 36864 total
        const int f  = e >> 9;
        const int r  = e & 511;
        const int L  = r >> 3;
        const int j  = r & 7;
        const int nb = f & 3;
        const int kk = (f >> 2) & 1;
        const int k9 = f >> 3;
        const int kci = kk * 32 + ((L >> 4) << 3) + j;
        const int n   = nb * 16 + (L & 15);
        __hip_bfloat16 bb = __float2bfloat16(W[k9 * 4096 + kci * 64 + n]);
        wfrag[e] = *reinterpret_cast<unsigned short*>(&bb);
    } else {
        gstats[threadIdx.x] = 0.f;
    }
}

__device__ __forceinline__ bf16x8 cvt8(float4 a, float4 b)
{
    union { bf16x8 v; __hip_bfloat162 h[4]; } u;
    u.h[0] = __float22bfloat162_rn(make_float2(a.x, a.y));
    u.h[1] = __float22bfloat162_rn(make_float2(a.z, a.w));
    u.h[2] = __float22bfloat162_rn(make_float2(b.x, b.y));
    u.h[3] = __float22bfloat162_rn(make_float2(b.z, b.w));
    return u.v;
}

// ---------------------------------------------------------------------------
// Conv via MFMA, depth-2 software-pipelined gathers.
// Block 256 thr = 4 waves; wave tile 64 rows x 64 cols (4x4 16x16 frags).
// K = 18 chunks of 32 (tap x half). While computing chunk c, the 8 loads of
// chunk c+1 are in flight -> compiler emits s_waitcnt vmcnt(8), never 0.
// ---------------------------------------------------------------------------
template<bool BF16PRE>
__global__ __launch_bounds__(256, 3)
void conv_mfma_kernel(const float* __restrict__ feat,
                      const unsigned short* __restrict__ featb,
                      const unsigned short* __restrict__ wfrag,
                      const float* __restrict__ bias,
                      const int*   __restrict__ nb9,
                      float* __restrict__ out,
                      float* __restrict__ gstats)
{
    __shared__ int IL[256 * 9];

    const int tid  = threadIdx.x;
    const int lane = tid & 63;
    const int wave = tid >> 6;
    const int quad = lane >> 4;
    const int l16  = lane & 15;
    const int rowbase = wave * 64;

    for (int i = tid; i < 256 * 9; i += 256)
        IL[i] = nb9[(size_t)blockIdx.x * 2304 + i];
    __syncthreads();

    f32x4 acc[4][4];
#pragma unroll
    for (int mb = 0; mb < 4; ++mb)
#pragma unroll
        for (int nbv = 0; nbv < 4; ++nbv)
            acc[mb][nbv] = (f32x4){0.f, 0.f, 0.f, 0.f};

    auto loadA = [&](int kk, const int* idx, bf16x8* A) {
#pragma unroll
        for (int mb = 0; mb < 4; ++mb) {
            const int id = idx[mb];
            const size_t row = (size_t)(id < 0 ? 0 : id);
            bf16x8 a;
            if (BF16PRE) {
                a = *(const bf16x8*)(featb + (row << 6) + kk * 32 + quad * 8);
            } else {
                const float* p = feat + (row << 6) + kk * 32 + quad * 8;
                a = cvt8(*(const float4*)p, *(const float4*)(p + 4));
            }
            A[mb] = (id < 0) ? (bf16x8)0 : a;
        }
    };
    auto loadB = [&](int chunk, bf16x8* B) {
#pragma unroll
        for (int nbv = 0; nbv < 4; ++nbv)
            B[nbv] = *(const bf16x8*)(wfrag + (((chunk << 2) + nbv) << 9) + lane * 8);
    };
    auto compute = [&](bf16x8* A, bf16x8* B) {
#pragma unroll
        for (int mb = 0; mb < 4; ++mb)
#pragma unroll
            for (int nbv = 0; nbv < 4; ++nbv)
                acc[mb][nbv] = __builtin_amdgcn_mfma_f32_16x16x32_bf16(
                    A[mb], B[nbv], acc[mb][nbv], 0, 0, 0);
    };

    int idx[4];
#pragma unroll
    for (int mb = 0; mb < 4; ++mb)
        idx[mb] = IL[(rowbase + mb * 16 + l16) * 9 + 0];

    bf16x8 A0[4], B0[4], A1[4], B1[4];
    loadA(0, idx, A0); loadB(0, B0);
    loadA(1, idx, A1); loadB(1, B1);

#pragma unroll 1
    for (int t = 0; t < 9; ++t) {
        int idxn[4];
        if (t < 8) {
#pragma unroll
            for (int mb = 0; mb < 4; ++mb)
                idxn[mb] = IL[(rowbase + mb * 16 + l16) * 9 + t + 1];
        }
        compute(A0, B0);                                   // chunk (t,0)
        if (t < 8) { loadA(0, idxn, A0); loadB((t + 1) * 2,     B0); }
        compute(A1, B1);                                   // chunk (t,1)
        if (t < 8) { loadA(1, idxn, A1); loadB((t + 1) * 2 + 1, B1); }
    }

    // ---- epilogue: bias, store out, BN partial sums ----
    const size_t row0 = (size_t)blockIdx.x * 256 + rowbase;
    float s[4], sq[4];
#pragma unroll
    for (int nbv = 0; nbv < 4; ++nbv) { s[nbv] = 0.f; sq[nbv] = 0.f; }

#pragma unroll
    for (int nbv = 0; nbv < 4; ++nbv) {
        const float b = bias[nbv * 16 + l16];
#pragma unroll
        for (int mb = 0; mb < 4; ++mb) {
            const f32x4 v = acc[mb][nbv];
#pragma unroll
            for (int i = 0; i < 4; ++i) {
                const float o = v[i] + b;
                out[(row0 + mb * 16 + quad * 4 + i) * 64 + nbv * 16 + l16] = o;
                s[nbv]  += o;
                sq[nbv] += o * o;
            }
        }
    }
#pragma unroll
    for (int nbv = 0; nbv < 4; ++nbv) {
        float ss = s[nbv], qq = sq[nbv];
        ss += __shfl_xor(ss, 16, 64);  qq += __shfl_xor(qq, 16, 64);
        ss += __shfl_xor(ss, 32, 64);  qq += __shfl_xor(qq, 32, 64);
        if (quad == 0) {
            atomicAdd(&gstats[nbv * 16 + l16],      ss);
            atomicAdd(&gstats[64 + nbv * 16 + l16], qq);
        }
    }
}

// ---------------------------------------------------------------------------
// BN apply (stats folded in: each thread derives scale/shift from sums).
// ---------------------------------------------------------------------------
__global__ void bn_apply_kernel(const float* __restrict__ out,
                                const float* __restrict__ gstats,
                                const float* __restrict__ gamma,
                                const float* __restrict__ beta,
                                float* __restrict__ out_bn)
{
    const size_t i  = (size_t)blockIdx.x * blockDim.x + threadIdx.x;  // float4 idx
    const int    c4 = ((int)i & 15) << 2;
    const float4 v   = ((const float4*)out)[i];
    const float4 sm  = *(const float4*)(gstats + c4);
    const float4 sv  = *(const float4*)(gstats + 64 + c4);
    const float4 gm  = *(const float4*)(gamma + c4);
    const float4 bt  = *(const float4*)(beta + c4);
    const float inv_n = 1.f / (float)N_TOTAL;
    float4 o;
#pragma unroll
    for (int j = 0; j < 4; ++j) {
        const float mean = (&sm.x)[j] * inv_n;
        const float var  = (&sv.x)[j] * inv_n - mean * mean;
        const float sc   = (&gm.x)[j] * rsqrtf(var + BN_EPS);
        const float sh   = (&bt.x)[j] - mean * sc;
        (&o.x)[j] = fmaf((&v.x)[j], sc, sh);
    }
    ((float4*)out_bn)[i] = o;
}

extern "C" void kernel_launch(void* const* d_in, const int* in_sizes, int n_in,
                              void* d_out, int out_size, void* d_ws, size_t ws_size,
                              hipStream_t stream)
{
    const float* feat  = (const float*)d_in[0];   // (N, 64)
    const float* W     = (const float*)d_in[1];   // (9, 64, 64)
    const float* bias  = (const float*)d_in[2];
    const float* gamma = (const float*)d_in[3];
    const float* beta  = (const float*)d_in[4];
    const int*   nb9   = (const int*)  d_in[5];   // (N, 9)

    float* out    = (float*)d_out;
    float* out_bn = out + (size_t)N_TOTAL * 64;

    float*          gstats = (float*)d_ws;
    unsigned short* wfrag  = (unsigned short*)((char*)d_ws + WFRAG_OFF);
    unsigned short* featb  = (unsigned short*)((char*)d_ws + FEATB_OFF);

    const bool use_featb =
        ws_size >= (size_t)FEATB_OFF + (size_t)N_TOTAL * 64 * sizeof(unsigned short);

    const int prep_grid = FEAT_BLOCKS + WPACK_BLOCKS + 1;
    if (use_featb) {
        prepare_kernel<true><<<prep_grid, 256, 0, stream>>>(feat, featb, W, wfrag, gstats);
        conv_mfma_kernel<true><<<N_TOTAL / 256, 256, 0, stream>>>(
            feat, featb, wfrag, bias, nb9, out, gstats);
    } else {
        prepare_kernel<false><<<prep_grid, 256, 0, stream>>>(feat, featb, W, wfrag, gstats);
        conv_mfma_kernel<false><<<N_TOTAL / 256, 256, 0, stream>>>(
            feat, featb, wfrag, bias, nb9, out, gstats);
    }
    bn_apply_kernel<<<(N_TOTAL * 64 / 4) / 256, 256, 0, stream>>>(
        out, gstats, gamma, beta, out_bn);
}

// Round 4
// 254.826 us; speedup vs baseline: 7.4921x; 1.2700x over previous
//
#include <hip/hip_runtime.h>
#include <hip/hip_bf16.h>

#define N_TOTAL 262144
#define BN_EPS  1e-3f

typedef float f32x4  __attribute__((ext_vector_type(4)));
typedef short bf16x8 __attribute__((ext_vector_type(8)));

typedef __attribute__((address_space(1))) const unsigned int as1cu;
typedef __attribute__((address_space(3))) unsigned int       as3u;

// ws layout:
//   floats [0, 4096)      : gstats replicas — 32 x (sum[64], sumsq[64])
//   floats [4096, 4224)   : scale[64], shift[64]
//   bytes  [17408, 91136) : wfrag — 72 B-frags x 64 lanes x 8 bf16
//   bytes  [131072, ...)  : 128B zero row, then featb (N x 64 bf16)
#define SCALE_F   4096
#define WFRAG_OFF 17408
#define FEATB_OFF 131072
#define FEAT_BLOCKS 16384
#define WPACK_BLOCKS 144

// ---------------------------------------------------------------------------
template<bool DO_FEAT>
__global__ void prepare_kernel(const float* __restrict__ feat,
                               unsigned short* __restrict__ featb_region,
                               const float* __restrict__ W,
                               unsigned short* __restrict__ wfrag,
                               float* __restrict__ gstats)
{
    const int b = blockIdx.x;
    if (b < FEAT_BLOCKS) {
        if (DO_FEAT) {
            const size_t i = (size_t)b * 256 + threadIdx.x;   // float4 units
            const float4 v = ((const float4*)feat)[i];
            union { __hip_bfloat162 h[2]; uint2 u; } p;
            p.h[0] = __float22bfloat162_rn(make_float2(v.x, v.y));
            p.h[1] = __float22bfloat162_rn(make_float2(v.z, v.w));
            ((uint2*)(featb_region + 64))[i] = p.u;           // +64: skip zero row
        }
    } else if (b < FEAT_BLOCKS + WPACK_BLOCKS) {
        const int e = (b - FEAT_BLOCKS) * 256 + threadIdx.x;
        const int f  = e >> 9;
        const int r  = e & 511;
        const int L  = r >> 3;
        const int j  = r & 7;
        const int nb = f & 3;
        const int kk = (f >> 2) & 1;
        const int k9 = f >> 3;
        const int kci = kk * 32 + ((L >> 4) << 3) + j;
        const int n   = nb * 16 + (L & 15);
        __hip_bfloat16 bb = __float2bfloat16(W[k9 * 4096 + kci * 64 + n]);
        wfrag[e] = *reinterpret_cast<unsigned short*>(&bb);
    } else {
        for (int i = threadIdx.x; i < 4096; i += 256) gstats[i] = 0.f;
        if (threadIdx.x < 64) featb_region[threadIdx.x] = 0;  // zero row
    }
}

// ---------------------------------------------------------------------------
// Conv via MFMA with async-LDS gather pipeline.
// Block 256 thr = 4 waves, 128 rows/block. Wave tile 32 rows x 64 cols.
// Per tap t: 4 global_load_lds_dwordx4 gathers (1KB each, per-lane addresses,
// frag-ordered LDS dest) issued 2 taps ahead; B-frags reg-loaded 1 tap ahead.
// Hand-placed s_waitcnt vmcnt(N) keeps the VMEM queue never-drained.
// ---------------------------------------------------------------------------
__global__ __launch_bounds__(256, 3)
void conv_mfma_kernel(const unsigned short* __restrict__ featb,  // after zero row
                      const unsigned short* __restrict__ wfrag,
                      const float* __restrict__ bias,
                      const int*   __restrict__ nb9,
                      float* __restrict__ out,
                      float* __restrict__ gstats)
{
    __shared__ int IL[128 * 9];
    __shared__ __align__(16) unsigned short Abuf[3 * 4 * 2 * 2 * 512]; // 48KB

    const int tid  = threadIdx.x;
    const int lane = tid & 63;
    const int wave = tid >> 6;
    const int quad = lane >> 4;
    const int l16  = lane & 15;
    const int rowbase = wave * 32;

    for (int i = tid; i < 128 * 9; i += 256)
        IL[i] = nb9[(size_t)blockIdx.x * 1152 + i];
    __syncthreads();

    // per-lane gather offsets (ushort units); invalid -> -64 = zero row
    int ofs[9][2];
#pragma unroll
    for (int t = 0; t < 9; ++t)
#pragma unroll
        for (int mb = 0; mb < 2; ++mb) {
            const int id = IL[(rowbase + mb * 16 + l16) * 9 + t];
            ofs[t][mb] = (id < 0) ? -64 : (id << 6);
        }

    f32x4 acc[2][4];
#pragma unroll
    for (int mb = 0; mb < 2; ++mb)
#pragma unroll
        for (int nb = 0; nb < 4; ++nb)
            acc[mb][nb] = (f32x4){0.f, 0.f, 0.f, 0.f};

    bf16x8 Bf[2][8];

    auto loadBtap = [&](int t) {
#pragma unroll
        for (int f = 0; f < 8; ++f)
            Bf[t & 1][f] = *(const bf16x8*)(wfrag + (t * 8 + f) * 512 + lane * 8);
    };
    auto asyncA = [&](int t) {
        const int buf = t % 3;
#pragma unroll
        for (int mb = 0; mb < 2; ++mb)
#pragma unroll
            for (int kk = 0; kk < 2; ++kk) {
                const unsigned short* g = featb + ofs[t][mb] + kk * 32 + quad * 8;
                unsigned short* l = &Abuf[(((buf * 4 + wave) * 2 + mb) * 2 + kk) * 512];
                __builtin_amdgcn_global_load_lds((as1cu*)g, (as3u*)l, 16, 0, 0);
            }
    };

    // prologue: queue = [B0(8), A0(4), A1(4)]
    loadBtap(0);
    asyncA(0);
    asyncA(1);

#pragma unroll
    for (int t = 0; t < 9; ++t) {
        if (t + 1 < 9) loadBtap(t + 1);
        if (t + 2 < 9) asyncA(t + 2);
        // queue accounting: drains exactly A(t),B(t); keeps [A(t+1),B(t+1),A(t+2)]
        if (t < 7)       asm volatile("s_waitcnt vmcnt(16)" ::: "memory");
        else if (t == 7) asm volatile("s_waitcnt vmcnt(12)" ::: "memory");
        else             asm volatile("s_waitcnt vmcnt(0)"  ::: "memory");

        const int buf = t % 3;
#pragma unroll
        for (int kk = 0; kk < 2; ++kk)
#pragma unroll
            for (int mb = 0; mb < 2; ++mb) {
                const bf16x8 a = *(const bf16x8*)
                    &Abuf[(((buf * 4 + wave) * 2 + mb) * 2 + kk) * 512 + lane * 8];
#pragma unroll
                for (int nb = 0; nb < 4; ++nb)
                    acc[mb][nb] = __builtin_amdgcn_mfma_f32_16x16x32_bf16(
                        a, Bf[t & 1][kk * 4 + nb], acc[mb][nb], 0, 0, 0);
            }
    }

    // ---- epilogue: bias, store out, BN partial sums (replica atomics) ----
    const size_t row0 = (size_t)blockIdx.x * 128 + rowbase;
    const int rep = (blockIdx.x & 31) * 128;
    float s[4], sq[4];
#pragma unroll
    for (int nb = 0; nb < 4; ++nb) { s[nb] = 0.f; sq[nb] = 0.f; }

#pragma unroll
    for (int nb = 0; nb < 4; ++nb) {
        const float b = bias[nb * 16 + l16];
#pragma unroll
        for (int mb = 0; mb < 2; ++mb) {
            const f32x4 v = acc[mb][nb];
#pragma unroll
            for (int i = 0; i < 4; ++i) {
                const float o = v[i] + b;
                out[(row0 + mb * 16 + quad * 4 + i) * 64 + nb * 16 + l16] = o;
                s[nb]  += o;
                sq[nb] += o * o;
            }
        }
    }
#pragma unroll
    for (int nb = 0; nb < 4; ++nb) {
        float ss = s[nb], qq = sq[nb];
        ss += __shfl_xor(ss, 16, 64);  qq += __shfl_xor(qq, 16, 64);
        ss += __shfl_xor(ss, 32, 64);  qq += __shfl_xor(qq, 32, 64);
        if (quad == 0) {
            atomicAdd(&gstats[rep + nb * 16 + l16],      ss);
            atomicAdd(&gstats[rep + 64 + nb * 16 + l16], qq);
        }
    }
}

// ---------------------------------------------------------------------------
// Fallback (tiny ws): correct but slow fp32 path. Not expected to run.
// ---------------------------------------------------------------------------
__global__ void conv_fallback_kernel(const float* __restrict__ feat,
                                     const float* __restrict__ W,
                                     const float* __restrict__ bias,
                                     const int* __restrict__ nb9,
                                     float* __restrict__ out,
                                     float* __restrict__ gstats)
{
    const int n = blockIdx.x;
    const int c = threadIdx.x;   // 64 threads
    float a = bias[c];
    for (int k = 0; k < 9; ++k) {
        const int id = nb9[(size_t)n * 9 + k];
        if (id >= 0) {
            const float* fr = feat + (size_t)id * 64;
            const float* wk = W + k * 4096 + c;
            for (int ci = 0; ci < 64; ++ci) a = fmaf(fr[ci], wk[ci * 64], a);
        }
    }
    out[(size_t)n * 64 + c] = a;
    atomicAdd(&gstats[(n & 31) * 128 + c], a);
    atomicAdd(&gstats[(n & 31) * 128 + 64 + c], a * a);
}

__global__ void zero_stats_kernel(float* __restrict__ gstats)
{
    for (int i = threadIdx.x + blockIdx.x * 256; i < 4096; i += 256 * 16)
        gstats[i] = 0.f;
}

// ---------------------------------------------------------------------------
__global__ void bn_stats_kernel(const float* __restrict__ gamma,
                                const float* __restrict__ beta,
                                float* __restrict__ gs)
{
    const int c = threadIdx.x;   // 64 threads
    float s = 0.f, q = 0.f;
#pragma unroll
    for (int r = 0; r < 32; ++r) { s += gs[r * 128 + c]; q += gs[r * 128 + 64 + c]; }
    const float inv_n = 1.f / (float)N_TOTAL;
    const float mean  = s * inv_n;
    const float var   = q * inv_n - mean * mean;
    const float sc    = gamma[c] * rsqrtf(var + BN_EPS);
    gs[SCALE_F + c]      = sc;
    gs[SCALE_F + 64 + c] = beta[c] - mean * sc;
}

__global__ void bn_apply_kernel(const float* __restrict__ out,
                                const float* __restrict__ gs,
                                float* __restrict__ out_bn)
{
    const size_t i  = (size_t)blockIdx.x * blockDim.x + threadIdx.x;  // float4 idx
    const int    c4 = ((int)i & 15) << 2;
    const float4 v  = ((const float4*)out)[i];
    const float4 sc = *(const float4*)(gs + SCALE_F + c4);
    const float4 sh = *(const float4*)(gs + SCALE_F + 64 + c4);
    float4 o;
    o.x = fmaf(v.x, sc.x, sh.x);
    o.y = fmaf(v.y, sc.y, sh.y);
    o.z = fmaf(v.z, sc.z, sh.z);
    o.w = fmaf(v.w, sc.w, sh.w);
    ((float4*)out_bn)[i] = o;
}

extern "C" void kernel_launch(void* const* d_in, const int* in_sizes, int n_in,
                              void* d_out, int out_size, void* d_ws, size_t ws_size,
                              hipStream_t stream)
{
    const float* feat  = (const float*)d_in[0];   // (N, 64)
    const float* W     = (const float*)d_in[1];   // (9, 64, 64)
    const float* bias  = (const float*)d_in[2];
    const float* gamma = (const float*)d_in[3];
    const float* beta  = (const float*)d_in[4];
    const int*   nb9   = (const int*)  d_in[5];   // (N, 9)

    float* out    = (float*)d_out;
    float* out_bn = out + (size_t)N_TOTAL * 64;

    float*          gstats       = (float*)d_ws;
    unsigned short* wfrag        = (unsigned short*)((char*)d_ws + WFRAG_OFF);
    unsigned short* featb_region = (unsigned short*)((char*)d_ws + FEATB_OFF);

    const bool use_featb =
        ws_size >= (size_t)FEATB_OFF + 128 + (size_t)N_TOTAL * 64 * sizeof(unsigned short);

    if (use_featb) {
        prepare_kernel<true><<<FEAT_BLOCKS + WPACK_BLOCKS + 1, 256, 0, stream>>>(
            feat, featb_region, W, wfrag, gstats);
        conv_mfma_kernel<<<N_TOTAL / 128, 256, 0, stream>>>(
            featb_region + 64, wfrag, bias, nb9, out, gstats);
    } else {
        zero_stats_kernel<<<16, 256, 0, stream>>>(gstats);
        conv_fallback_kernel<<<N_TOTAL, 64, 0, stream>>>(
            feat, W, bias, nb9, out, gstats);
    }
    bn_stats_kernel<<<1, 64, 0, stream>>>(gamma, beta, gstats);
    bn_apply_kernel<<<(N_TOTAL * 64 / 4) / 256, 256, 0, stream>>>(out, gstats, out_bn);
}